// Round 4
// baseline (405.961 us; speedup 1.0000x reference)
//
#include <hip/hip_runtime.h>
#include <hip/hip_bf16.h>
#include <cmath>

#define Bz 32
#define Tz 2048
#define Vz 32
#define Cz 64   // chunks per batch
#define Lz 32   // steps per chunk
#define WPB 4   // waves (chunks) per block in kernel A

typedef short short8 __attribute__((ext_vector_type(8)));
typedef float f32x16 __attribute__((ext_vector_type(16)));
typedef float f32x4  __attribute__((ext_vector_type(4)));

static __device__ __forceinline__ unsigned short f2bf(float x) {
    unsigned u = __builtin_bit_cast(unsigned, x);
    u += 0x7FFFu + ((u >> 16) & 1u);          // RNE
    return (unsigned short)(u >> 16);
}

static __device__ __forceinline__ void gl_lds16(const float* g, float* l) {
    __builtin_amdgcn_global_load_lds(
        (const __attribute__((address_space(1))) void*)g,
        (__attribute__((address_space(3))) void*)l, 16, 0, 0);
}

// ---------------- Kernel A: per-(batch,chunk) semiring matrix product ----------------
// One wave per chunk. State: E (32x32, column-scaled linear, in MFMA C-layout regs),
// c_j (column log-scales). Step: M''[k,j] = c_k + s_t[k,j] + trans[k,j];
// d_j = colmax; G = exp(M''-d_j); E_new = E @ G (2x mfma_32x32x16_bf16);
// col-renorm E_new, c_j = d_j + log(colmax). Writes P[i,j] = c_j + log E[i,j].
// NOTE: operand k-slot mapping (k = 8*(lane>>5)+e) need not match HW — any
// bijection cancels between A and B as long as both use the same indexing.
// Only the C/D layout must be exact (row=(r&3)+8*(r>>2)+4*(lane>>5), col=lane&31;
// HW-verified m74/m101).
__global__ void __launch_bounds__(256) crf_chunks(
    const float* __restrict__ inputs, const float* __restrict__ trans,
    const int* __restrict__ targets, float* __restrict__ Pout,
    float* __restrict__ numpart)
{
    __shared__ __align__(16) float trans_lds[1024];
    __shared__ __align__(16) float sbuf[WPB][3 * 1024];      // 3-deep s_t buffer / wave
    __shared__ __align__(16) unsigned short elds[WPB][32 * 40]; // E as bf16, pitch 40
    __shared__ __align__(16) float cbuf[WPB][32];

    const int tid  = threadIdx.x;
    const int lane = tid & 63;
    const int wid  = tid >> 6;
    const int gid  = __builtin_amdgcn_readfirstlane(blockIdx.x * WPB + wid);
    const int b    = gid >> 6;          // / Cz
    const int c    = gid & (Cz - 1);    // % Cz

    const int h = lane >> 5;
    const int j = lane & 31;            // B-frag col / A-frag row / C col
    const int kbase = 8 * h;

    // transition values at this lane's B-fragment (k,j) positions — constant, keep in regs
    float tr[16];
#pragma unroll
    for (int e = 0; e < 8; ++e) {
        tr[e]     = trans[(kbase + e) * Vz + j];
        tr[8 + e] = trans[(16 + kbase + e) * Vz + j];
    }

    // stage transition into LDS for the numerator gather
    ((float4*)trans_lds)[tid] = ((const float4*)trans)[tid];
    __syncthreads();

    const float* src = inputs + ((size_t)b * Tz + (size_t)c * Lz) * (Vz * Vz);
    const int*   tgb = targets + b * (Tz + 1) + c * Lz;
    int tgv = (lane < Lz + 1) ? tgb[lane] : 0;   // target path for this chunk

    // ---- pipeline prologue: stage s_0, s_1 ----
    float* sw = sbuf[wid];
    {
        const float* g0 = src + lane * 4;
#pragma unroll
        for (int q = 0; q < 4; ++q) gl_lds16(g0 + q * 256, sw + q * 256);
        const float* g1 = src + 1024 + lane * 4;
#pragma unroll
        for (int q = 0; q < 4; ++q) gl_lds16(g1 + q * 256, sw + 1024 + q * 256);
    }

    f32x16 p;
    float cj = 0.f;
    float epart = 0.f;
    float ckr[16];
#pragma unroll
    for (int e = 0; e < 16; ++e) ckr[e] = 0.f;

    for (int t = 0; t < Lz; ++t) {
        if (t + 2 < Lz) {   // prefetch depth 2
            const float* g = src + (t + 2) * 1024 + lane * 4;
            float* dst = sw + ((t + 2) % 3) * 1024;
#pragma unroll
            for (int q = 0; q < 4; ++q) gl_lds16(g + q * 256, dst + q * 256);
        }
        // counted vmcnt: exactly 4 global_load_lds per staged step, nothing else
        const int rem = Lz - 1 - t;
        if (rem >= 2)      { asm volatile("s_waitcnt vmcnt(8)" ::: "memory"); }
        else if (rem == 1) { asm volatile("s_waitcnt vmcnt(4)" ::: "memory"); }
        else               { asm volatile("s_waitcnt vmcnt(0)" ::: "memory"); }
        __builtin_amdgcn_sched_barrier(0);

        const float* sb = sw + (t % 3) * 1024;

        // numerator emit+trans along target path — broadcast LDS read, ~free
        {
            int yp = __shfl(tgv, t, 64);
            int yn = __shfl(tgv, t + 1, 64);
            int eidx = yp * Vz + yn;
            epart += sb[eidx] + trans_lds[eidx];
        }

        // shifted scores at lane's (k,j) positions
        float m[16];
#pragma unroll
        for (int e = 0; e < 8; ++e) {
            m[e]     = sb[(kbase + e) * Vz + j]      + tr[e]     + ckr[e];
            m[8 + e] = sb[(16 + kbase + e) * Vz + j] + tr[8 + e] + ckr[8 + e];
        }
        float d = m[0];
#pragma unroll
        for (int e = 1; e < 16; ++e) d = fmaxf(d, m[e]);
        d = fmaxf(d, __shfl_xor(d, 32, 64));   // lanes l, l^32 share column j

        short8 B1, B2;   // G fragments (bf16), k = kbase+e (+16 for B2)
#pragma unroll
        for (int e = 0; e < 8; ++e) {
            B1[e] = (short)f2bf(__expf(m[e] - d));
            B2[e] = (short)f2bf(__expf(m[8 + e] - d));
        }

        short8 A1, A2;   // E fragments: row = j, k = kbase+e (+16)
        if (t == 0) {    // E = Identity (exact)
#pragma unroll
            for (int e = 0; e < 8; ++e) {
                A1[e] = (short)((kbase + e == j) ? 0x3F80 : 0);
                A2[e] = (short)((16 + kbase + e == j) ? 0x3F80 : 0);
            }
        } else {
            const unsigned short* ew = elds[wid] + j * 40;
            A1 = *(const short8*)(ew + kbase);
            A2 = *(const short8*)(ew + 16 + kbase);
        }

        f32x16 z = {};
        p = __builtin_amdgcn_mfma_f32_32x32x16_bf16(A1, B1, z, 0, 0, 0);
        p = __builtin_amdgcn_mfma_f32_32x32x16_bf16(A2, B2, p, 0, 0, 0);

        // column renorm: colmax in [1,32] by construction
        float mj = p[0];
#pragma unroll
        for (int r = 1; r < 16; ++r) mj = fmaxf(mj, p[r]);
        mj = fmaxf(mj, __shfl_xor(mj, 32, 64));
        float inv = 1.0f / mj;
#pragma unroll
        for (int r = 0; r < 16; ++r) p[r] *= inv;
        cj = d + __logf(mj);

        // store E (bf16) for next step's A-frags; C-layout row formula (m74/m101)
        unsigned short* ew = elds[wid];
#pragma unroll
        for (int r = 0; r < 16; ++r) {
            const int row = (r & 3) + 8 * (r >> 2) + 4 * h;
            ew[row * 40 + j] = f2bf(p[r]);
        }
        if (lane < 32) cbuf[wid][j] = cj;
        {   // redistribute c from j-indexed to this lane's k positions
            const float* cb = cbuf[wid];
            f32x4 c0 = *(const f32x4*)(cb + kbase);
            f32x4 c1 = *(const f32x4*)(cb + kbase + 4);
            f32x4 c2 = *(const f32x4*)(cb + 16 + kbase);
            f32x4 c3 = *(const f32x4*)(cb + 16 + kbase + 4);
#pragma unroll
            for (int v = 0; v < 4; ++v) {
                ckr[v] = c0[v]; ckr[4 + v] = c1[v];
                ckr[8 + v] = c2[v]; ckr[12 + v] = c3[v];
            }
        }
    }

    // P = c_j + log E  (log(0) = -inf is fine downstream)
    float* Pc = Pout + (size_t)gid * 1024;
#pragma unroll
    for (int r = 0; r < 16; ++r) {
        const int row = (r & 3) + 8 * (r >> 2) + 4 * h;
        Pc[row * Vz + j] = cj + __logf(p[r]);
    }
    if (lane == 0) numpart[gid] = epart;
}

// ---------------- Kernel B: sequential combine over chunk matrices + output ----------------
// One wave per batch. alpha held distributed (lane l owns column l&31, duplicated
// across halves). Depth-4 named-buffer prefetch covers ~900cy HBM latency;
// pairwise-tree reductions shorten the serial per-chunk chain.
#define LOADQ(buf, chunk)                                                  \
    do { if ((chunk) < Cz) {                                               \
        const float* Pn = Pb + (size_t)(chunk) * 1024;                     \
        _Pragma("unroll")                                                  \
        for (int ii = 0; ii < 16; ++ii) buf[ii] = Pn[(hh + ii) * 32 + j];  \
    } } while (0)

#define PROCQ(buf)                                                         \
    do {                                                                   \
        float x[16];                                                       \
        _Pragma("unroll")                                                  \
        for (int ii = 0; ii < 16; ++ii)                                    \
            x[ii] = __shfl(al, hh + ii, 64) + buf[ii];                     \
        float u0 = fmaxf(x[0], x[1]),  u1 = fmaxf(x[2], x[3]);             \
        float u2 = fmaxf(x[4], x[5]),  u3 = fmaxf(x[6], x[7]);             \
        float u4 = fmaxf(x[8], x[9]),  u5 = fmaxf(x[10], x[11]);           \
        float u6 = fmaxf(x[12], x[13]), u7 = fmaxf(x[14], x[15]);          \
        u0 = fmaxf(u0, u1); u2 = fmaxf(u2, u3);                            \
        u4 = fmaxf(u4, u5); u6 = fmaxf(u6, u7);                            \
        u0 = fmaxf(u0, u2); u4 = fmaxf(u4, u6);                            \
        float mx = fmaxf(u0, u4);                                          \
        mx = fmaxf(mx, __shfl_xor(mx, 32, 64));                            \
        float e[16];                                                       \
        _Pragma("unroll")                                                  \
        for (int ii = 0; ii < 16; ++ii) e[ii] = __expf(x[ii] - mx);        \
        float s0 = e[0] + e[1],   s1 = e[2] + e[3];                        \
        float s2 = e[4] + e[5],   s3 = e[6] + e[7];                        \
        float s4 = e[8] + e[9],   s5 = e[10] + e[11];                      \
        float s6 = e[12] + e[13], s7 = e[14] + e[15];                      \
        s0 += s1; s2 += s3; s4 += s5; s6 += s7;                            \
        s0 += s2; s4 += s6;                                                \
        float s = s0 + s4;                                                 \
        s += __shfl_xor(s, 32, 64);                                        \
        al = mx + __logf(s);                                               \
    } while (0)

__global__ void __launch_bounds__(64) crf_combine(
    const float* __restrict__ Pout, const float* __restrict__ numpart,
    const float* __restrict__ initial, const float* __restrict__ fin,
    const int* __restrict__ targets, float* __restrict__ out)
{
    const int lane = threadIdx.x;
    const int b = blockIdx.x;
    const int h = lane >> 5;
    const int j = lane & 31;
    const int hh = h * 16;

    const float* Pb = Pout + (size_t)b * Cz * 1024;
    float al = initial[j];            // alpha[column j], duplicated across halves

    float q0[16], q1[16], q2[16], q3[16];
    LOADQ(q0, 0); LOADQ(q1, 1); LOADQ(q2, 2); LOADQ(q3, 3);

    for (int cc = 0; cc < Cz; cc += 4) {
        PROCQ(q0); LOADQ(q0, cc + 4);
        PROCQ(q1); LOADQ(q1, cc + 5);
        PROCQ(q2); LOADQ(q2, cc + 6);
        PROCQ(q3); LOADQ(q3, cc + 7);
    }

    // denom = lse_j(alpha[j] + final[j]); halves duplicate -> mask h==1 with -inf,
    // cross-half reduce first so -inf never meets -inf on the live path
    float mm = (h == 0) ? (al + fin[j]) : -INFINITY;
    float ss = 1.f;
#pragma unroll
    for (int off = 32; off >= 1; off >>= 1) {
        float om = __shfl_xor(mm, off, 64);
        float os = __shfl_xor(ss, off, 64);
        float nm = fmaxf(mm, om);
        ss = ss * __expf(mm - nm) + os * __expf(om - nm);
        mm = nm;
    }
    float denom = mm + __logf(ss);

    float np = numpart[b * Cz + lane];   // Cz == 64 == blockDim
#pragma unroll
    for (int off = 32; off >= 1; off >>= 1) np += __shfl_xor(np, off, 64);

    if (lane == 0) {
        const int* tg = targets + b * (Tz + 1);
        out[b] = np + initial[tg[0]] + fin[tg[Tz]] - denom;
    }
}

extern "C" void kernel_launch(void* const* d_in, const int* in_sizes, int n_in,
                              void* d_out, int out_size, void* d_ws, size_t ws_size,
                              hipStream_t stream) {
    const float* inputs  = (const float*)d_in[0];
    const float* trans   = (const float*)d_in[1];
    const float* initial = (const float*)d_in[2];
    const float* fin     = (const float*)d_in[3];
    const int*   targets = (const int*)d_in[4];

    float* Pout    = (float*)d_ws;                       // 2048 * 1024 fp32 = 8 MB
    float* numpart = Pout + (size_t)Bz * Cz * 1024;      // + 2048 fp32

    hipLaunchKernelGGL(crf_chunks, dim3(Bz * Cz / WPB), dim3(256), 0, stream,
                       inputs, trans, targets, Pout, numpart);
    hipLaunchKernelGGL(crf_combine, dim3(Bz), dim3(64), 0, stream,
                       Pout, numpart, initial, fin, targets, (float*)d_out);
}